// Round 5
// baseline (2988.977 us; speedup 1.0000x reference)
//
#include <hip/hip_runtime.h>
#include <math.h>

// Problem constants (reference: BS=32, N=M=1024, eps=0.1, 200 iters)
#define BS    32
#define N     1024
#define M     1024
#define ITERS 200

// 8 WGs per batch, 512 threads each -> grid 256 = 1 block/CU.
// Each lane holds its 16 rows x 16 cols of quantized-G in 32 uint4 VGPRs:
// the iteration loop touches NO global/LDS memory for G at all.
#define WPB   8
#define ROWS  (N / WPB)           // 128 rows per WG
#define T     512                 // 8 waves
#define NW    (T / 64)
#define RPW   (ROWS / NW)         // 16 rows per wave

// ws layout: counters + double-buffered column partials (2 MB total)
#define CNT_BYTES   4096
#define PART_OFF    ((size_t)CNT_BYTES)
#define PART_BYTES  ((size_t)2 * BS * WPB * M * 4)
#define WS_NEEDED   (PART_OFF + PART_BYTES)

// unpack two u16 from a 32-bit word to floats (raw, unscaled)
__device__ __forceinline__ float2 upair(unsigned w) {
    return make_float2((float)(w & 0xffffu), (float)(w >> 16));
}

// Ghat = round(65535 * exp(-10*C)).  All 1/65535 scales cancel:
//   u' = MU / (Ghat . v)   ==  u/65535
//   col = sum_i u'*Ghat    ==  (u^T G) exactly
//   Gamma*n = u' * Ghat * v * N
__device__ __forceinline__ unsigned qq(float c0, float c1) {
    const float KE = -14.4269504088896340f;   // -10*log2(e)
    unsigned a = __float2uint_rn(65535.0f * __builtin_amdgcn_exp2f(KE * c0));
    unsigned b = __float2uint_rn(65535.0f * __builtin_amdgcn_exp2f(KE * c1));
    return a | (b << 16);
}

__global__ __launch_bounds__(T, 2) void sinkhorn_reg(
    const float* __restrict__ C,
    float* __restrict__ Gout,            // d_out: final Gamma*n only
    unsigned* __restrict__ cnt,          // [BS] stride-32 uints
    float* __restrict__ partials)        // [2][BS][WPB][M]
{
    const int bid  = blockIdx.x;
    const int b    = bid & (BS - 1);   // round-robin dispatch -> batch per XCD
    const int k    = bid >> 5;         // 0..7
    const int tid  = threadIdx.x;
    const int lane = tid & 63;
    const int wave = tid >> 6;

    const size_t sl = ((size_t)b * N + (size_t)k * ROWS) * M;
    const float MU = 1.0f / (float)N;
    const float NU = 1.0f / (float)M;

    __shared__ float v_lds[M];            // 4 KB
    __shared__ float u_lds[ROWS];         // 512 B
    __shared__ float part[NW][M];         // 32 KB
    __shared__ int   sameflag;

    // Register-resident quantized G: lane covers, per row,
    // cols {4l..4l+3},{256+4l..},{512+4l..},{768+4l..} (qA = first two groups)
    uint4 qA[RPW], qB[RPW];

    // ---- prologue: read own 128 rows of C, quantize into registers ----
    #pragma unroll
    for (int rr = 0; rr < RPW; ++rr) {
        const int row = wave * RPW + rr;
        const float4* cr = (const float4*)(C + sl + (size_t)row * M);
        float4 a0 = cr[lane],        a1 = cr[64 + lane];
        float4 b0 = cr[128 + lane],  b1 = cr[192 + lane];
        qA[rr].x = qq(a0.x, a0.y);  qA[rr].y = qq(a0.z, a0.w);
        qA[rr].z = qq(a1.x, a1.y);  qA[rr].w = qq(a1.z, a1.w);
        qB[rr].x = qq(b0.x, b0.y);  qB[rr].y = qq(b0.z, b0.w);
        qB[rr].z = qq(b1.x, b1.y);  qB[rr].w = qq(b1.z, b1.w);
    }
    ((float2*)v_lds)[tid] = make_float2(1.0f / M, 1.0f / M);
    float2 vold = make_float2(1.0f / M, 1.0f / M);
    __syncthreads();

    unsigned* mycnt = cnt + b * 32;
    const float4* v4 = (const float4*)v_lds;
    float4 vra0 = v4[lane],       vra1 = v4[64 + lane],
           vrb0 = v4[128 + lane], vrb1 = v4[192 + lane];

    bool converged = false;
    for (int t = 0; t < ITERS && !converged; ++t) {
        const int par = t & 1;
        // ---- fused sweep over own 16 rows/wave, all from registers ----
        float4 ca0 = make_float4(0,0,0,0), ca1 = make_float4(0,0,0,0),
               cb0 = make_float4(0,0,0,0), cb1 = make_float4(0,0,0,0);
        #pragma unroll
        for (int rr = 0; rr < RPW; ++rr) {
            float2 g0 = upair(qA[rr].x), g1 = upair(qA[rr].y),
                   g2 = upair(qA[rr].z), g3 = upair(qA[rr].w);
            float2 h0 = upair(qB[rr].x), h1 = upair(qB[rr].y),
                   h2 = upair(qB[rr].z), h3 = upair(qB[rr].w);
            float pa = (g0.x*vra0.x + g0.y*vra0.y) + (g1.x*vra0.z + g1.y*vra0.w);
            float pb = (g2.x*vra1.x + g2.y*vra1.y) + (g3.x*vra1.z + g3.y*vra1.w);
            float pc = (h0.x*vrb0.x + h0.y*vrb0.y) + (h1.x*vrb0.z + h1.y*vrb0.w);
            float pd = (h2.x*vrb1.x + h2.y*vrb1.y) + (h3.x*vrb1.z + h3.y*vrb1.w);
            float dot = (pa + pb) + (pc + pd);
            #pragma unroll
            for (int off = 32; off > 0; off >>= 1)
                dot += __shfl_xor(dot, off, 64);
            const float ui = MU / dot;          // u' = u/65535 (scale folded)
            if (lane == 0) u_lds[wave * RPW + rr] = ui;
            ca0.x += ui*g0.x; ca0.y += ui*g0.y; ca0.z += ui*g1.x; ca0.w += ui*g1.y;
            ca1.x += ui*g2.x; ca1.y += ui*g2.y; ca1.z += ui*g3.x; ca1.w += ui*g3.y;
            cb0.x += ui*h0.x; cb0.y += ui*h0.y; cb0.z += ui*h1.x; cb0.w += ui*h1.y;
            cb1.x += ui*h2.x; cb1.y += ui*h2.y; cb1.z += ui*h3.x; cb1.w += ui*h3.y;
        }
        // wave's column partials -> LDS (contiguous per lane: conflict-free)
        {
            float4* pw = (float4*)part[wave];
            pw[lane]       = ca0;
            pw[64 + lane]  = ca1;
            pw[128 + lane] = cb0;
            pw[192 + lane] = cb1;
        }
        __syncthreads();
        // combine 8 waves (float2 per thread), write WG partial (coalesced)
        {
            if (tid == 0) sameflag = 1;
            float2 s = make_float2(0.0f, 0.0f);
            #pragma unroll
            for (int w = 0; w < NW; ++w) {
                float2 q = ((const float2*)part[w])[tid];
                s.x += q.x; s.y += q.y;
            }
            float2* pg = (float2*)(partials +
                (((size_t)par * BS + b) * WPB + k) * M);
            pg[tid] = s;
        }
        __syncthreads();
        // ---- single 8-wide inter-WG barrier for this batch ----
        if (tid == 0) {
            __hip_atomic_fetch_add(mycnt, 1u, __ATOMIC_RELEASE,
                                   __HIP_MEMORY_SCOPE_AGENT);
            const unsigned tgt = (unsigned)WPB * (unsigned)(t + 1);
            while (__hip_atomic_load(mycnt, __ATOMIC_ACQUIRE,
                                     __HIP_MEMORY_SCOPE_AGENT) < tgt)
                __builtin_amdgcn_s_sleep(1);
        }
        __syncthreads();
        // ---- v = NU / sum_p partial[p]  (fixed order; identical bits in all
        //      8 WGs -> uniform local early-exit decision) ----
        {
            const float2* pall = (const float2*)(partials +
                ((size_t)par * BS + b) * ((size_t)WPB * M));
            float2 s = pall[tid];
            #pragma unroll
            for (int p = 1; p < WPB; ++p) {
                float2 q = pall[(size_t)p * (M / 2) + tid];
                s.x += q.x; s.y += q.y;
            }
            float2 vnew = make_float2(NU / s.x, NU / s.y);
            if ((__float_as_uint(vnew.x) != __float_as_uint(vold.x)) ||
                (__float_as_uint(vnew.y) != __float_as_uint(vold.y)))
                sameflag = 0;
            vold = vnew;
            ((float2*)v_lds)[tid] = vnew;
        }
        __syncthreads();
        vra0 = v4[lane];       vra1 = v4[64 + lane];
        vrb0 = v4[128 + lane]; vrb1 = v4[192 + lane];
        // Bitwise fixed point: v_t == v_{t-1} -> all later iters identical.
        converged = (sameflag != 0);
    }

    // ---- epilogue: Gamma*n = u' * Ghat * v * N (scales cancel) ----
    const float nN = (float)N;
    #pragma unroll
    for (int rr = 0; rr < RPW; ++rr) {
        const int row = wave * RPW + rr;
        const float un = u_lds[row] * nN;
        float2 g0 = upair(qA[rr].x), g1 = upair(qA[rr].y),
               g2 = upair(qA[rr].z), g3 = upair(qA[rr].w);
        float2 h0 = upair(qB[rr].x), h1 = upair(qB[rr].y),
               h2 = upair(qB[rr].z), h3 = upair(qB[rr].w);
        float4* o4 = (float4*)(Gout + sl + (size_t)row * M);
        o4[lane]       = make_float4(un*g0.x*vra0.x, un*g0.y*vra0.y,
                                     un*g1.x*vra0.z, un*g1.y*vra0.w);
        o4[64 + lane]  = make_float4(un*g2.x*vra1.x, un*g2.y*vra1.y,
                                     un*g3.x*vra1.z, un*g3.y*vra1.w);
        o4[128 + lane] = make_float4(un*h0.x*vrb0.x, un*h0.y*vrb0.y,
                                     un*h1.x*vrb0.z, un*h1.y*vrb0.w);
        o4[192 + lane] = make_float4(un*h2.x*vrb1.x, un*h2.y*vrb1.y,
                                     un*h3.x*vrb1.z, un*h3.y*vrb1.w);
    }
}

extern "C" void kernel_launch(void* const* d_in, const int* in_sizes, int n_in,
                              void* d_out, int out_size, void* d_ws, size_t ws_size,
                              hipStream_t stream) {
    (void)in_sizes; (void)n_in; (void)out_size;

    const float* C = (const float*)d_in[0];
    float* Gout = (float*)d_out;
    char* ws = (char*)d_ws;

    if (ws_size < WS_NEEDED) return;   // fail loudly (output stays poisoned)

    // Re-zero barrier counters every launch (graph-replay safe).
    hipMemsetAsync(d_ws, 0, CNT_BYTES, stream);

    unsigned* cnt   = (unsigned*)ws;
    float* partials = (float*)(ws + PART_OFF);
    sinkhorn_reg<<<dim3(BS * WPB), dim3(T), 0, stream>>>(
        C, Gout, cnt, partials);
}

// Round 6
// 1691.998 us; speedup vs baseline: 1.7665x; 1.7665x over previous
//
#include <hip/hip_runtime.h>
#include <math.h>

// Problem constants (reference: BS=32, N=M=1024, eps=0.1, 200 iters)
#define BS    32
#define N     1024
#define M     1024
#define ITERS 200

// 8 WGs per batch, 512 threads each -> grid 256 = 1 WG/CU.
// On-chip G residency per WG (256 KB) split:
//   rows [0,64):   registers — 16 uint4 (64 VGPR) per lane
//   rows [64,128): LDS       — packed u16, 128 KB
// The iteration sweep touches NO global memory.
#define WPB   8
#define ROWS  (N / WPB)      // 128 rows per WG
#define T     512            // 8 waves
#define NW    (T / 64)
#define HR    8              // register rows per wave
#define HL    8              // LDS rows per wave
#define HROWS (NW * HR)      // 64

// ws layout: counters + double-buffered column partials (~2 MB)
#define CNT_BYTES  4096
#define PART_OFF   ((size_t)CNT_BYTES)
#define PART_BYTES ((size_t)2 * BS * WPB * M * 4)
#define WS_NEEDED  (PART_OFF + PART_BYTES)

// unpack two u16 from a 32-bit word to floats (raw, unscaled)
__device__ __forceinline__ float2 upair(unsigned w) {
    return make_float2((float)(w & 0xffffu), (float)(w >> 16));
}

// Ghat = round(65535 * exp(-10*C)).  All 1/65535 scales cancel:
//   u' = MU / (Ghat . v) == u/65535 ; col = sum u'*Ghat == u^T G ;
//   Gamma*n = u' * Ghat * v * N
__device__ __forceinline__ unsigned qq(float c0, float c1) {
    const float KE = -14.4269504088896340f;   // -10*log2(e)
    unsigned a = __float2uint_rn(65535.0f * __builtin_amdgcn_exp2f(KE * c0));
    unsigned b = __float2uint_rn(65535.0f * __builtin_amdgcn_exp2f(KE * c1));
    return a | (b << 16);
}

#define ADD4(d, s) do { d.x += s.x; d.y += s.y; d.z += s.z; d.w += s.w; } while (0)

__global__ __launch_bounds__(T, 2) void sinkhorn_hybrid(
    const float* __restrict__ C,
    float* __restrict__ Gout,            // d_out: final Gamma*n only
    unsigned* __restrict__ cnt,          // [BS] stride-32 uints
    float* __restrict__ partials)        // [2][BS][WPB][M]
{
    const int bid  = blockIdx.x;
    const int b    = bid & (BS - 1);
    const int k    = bid >> 5;           // 0..7
    const int tid  = threadIdx.x;
    const int lane = tid & 63;
    const int wave = tid >> 6;

    const size_t sl = ((size_t)b * N + (size_t)k * ROWS) * M;
    const float MU = 1.0f / (float)N;
    const float NU = 1.0f / (float)M;

    // LDS: 131072 (G) + 16384 (tree) + 4096 (v) + 4  ~= 148 KB
    __shared__ uint4 Glds[HROWS][M / 8];  // row: 128 uint4 slots (packed u16)
    __shared__ float part4[4][M];         // pairwise wave-combine tree
    __shared__ float v_lds[M];
    __shared__ int   sameflag;

    // Register-resident half: lane covers, per row, cols
    // {4l..4l+3},{256+4l..},{512+4l..},{768+4l..}; qA = first two groups.
    uint4 qA[HR], qB[HR];

    // ---- prologue: quantize own 128 rows (64 -> regs, 64 -> LDS) ----
    #pragma unroll
    for (int i = 0; i < HR; ++i) {
        const int row = wave * HR + i;
        const float4* cr = (const float4*)(C + sl + (size_t)row * M);
        float4 a0 = cr[lane],       a1 = cr[64 + lane];
        float4 b0 = cr[128 + lane], b1 = cr[192 + lane];
        qA[i].x = qq(a0.x, a0.y);  qA[i].y = qq(a0.z, a0.w);
        qA[i].z = qq(a1.x, a1.y);  qA[i].w = qq(a1.z, a1.w);
        qB[i].x = qq(b0.x, b0.y);  qB[i].y = qq(b0.z, b0.w);
        qB[i].z = qq(b1.x, b1.y);  qB[i].w = qq(b1.z, b1.w);
    }
    #pragma unroll
    for (int i = 0; i < HL; ++i) {
        const int row = HROWS + wave * HL + i;
        const float4* cr = (const float4*)(C + sl + (size_t)row * M);
        float4 a0 = cr[lane],       a1 = cr[64 + lane];
        float4 b0 = cr[128 + lane], b1 = cr[192 + lane];
        uint4 oa, ob;
        oa.x = qq(a0.x, a0.y);  oa.y = qq(a0.z, a0.w);
        oa.z = qq(a1.x, a1.y);  oa.w = qq(a1.z, a1.w);
        ob.x = qq(b0.x, b0.y);  ob.y = qq(b0.z, b0.w);
        ob.z = qq(b1.x, b1.y);  ob.w = qq(b1.z, b1.w);
        Glds[wave * HL + i][lane]      = oa;
        Glds[wave * HL + i][64 + lane] = ob;
    }
    ((float2*)v_lds)[tid] = make_float2(1.0f / M, 1.0f / M);
    float2 vold = make_float2(1.0f / M, 1.0f / M);
    __syncthreads();

    unsigned* mycnt = cnt + b * 32;
    const float4* v4 = (const float4*)v_lds;
    float4 vra0 = v4[lane],       vra1 = v4[64 + lane],
           vrb0 = v4[128 + lane], vrb1 = v4[192 + lane];

    float ureg[2 * HR];   // u for own 16 rows (static-indexed)
    bool converged = false;

    for (int t = 0; t < ITERS && !converged; ++t) {
        const int par = t & 1;
        float4 ca0 = make_float4(0,0,0,0), ca1 = make_float4(0,0,0,0),
               cb0 = make_float4(0,0,0,0), cb1 = make_float4(0,0,0,0);

        auto dorow = [&](uint4 qa, uint4 qb) -> float {
            float2 g0 = upair(qa.x), g1 = upair(qa.y),
                   g2 = upair(qa.z), g3 = upair(qa.w);
            float2 h0 = upair(qb.x), h1 = upair(qb.y),
                   h2 = upair(qb.z), h3 = upair(qb.w);
            float pa = (g0.x*vra0.x + g0.y*vra0.y) + (g1.x*vra0.z + g1.y*vra0.w);
            float pb = (g2.x*vra1.x + g2.y*vra1.y) + (g3.x*vra1.z + g3.y*vra1.w);
            float pc = (h0.x*vrb0.x + h0.y*vrb0.y) + (h1.x*vrb0.z + h1.y*vrb0.w);
            float pd = (h2.x*vrb1.x + h2.y*vrb1.y) + (h3.x*vrb1.z + h3.y*vrb1.w);
            float dot = (pa + pb) + (pc + pd);
            #pragma unroll
            for (int off = 32; off > 0; off >>= 1)
                dot += __shfl_xor(dot, off, 64);
            float ui = MU / dot;
            ca0.x += ui*g0.x; ca0.y += ui*g0.y; ca0.z += ui*g1.x; ca0.w += ui*g1.y;
            ca1.x += ui*g2.x; ca1.y += ui*g2.y; ca1.z += ui*g3.x; ca1.w += ui*g3.y;
            cb0.x += ui*h0.x; cb0.y += ui*h0.y; cb0.z += ui*h1.x; cb0.w += ui*h1.y;
            cb1.x += ui*h2.x; cb1.y += ui*h2.y; cb1.z += ui*h3.x; cb1.w += ui*h3.y;
            return ui;
        };

        // ---- sweep: 8 reg rows + 8 LDS rows per wave, interleaved ----
        #pragma unroll
        for (int i = 0; i < HR; ++i) {
            uint4 la = Glds[wave * HL + i][lane];        // issue LDS reads
            uint4 lb = Glds[wave * HL + i][64 + lane];   // early; VALU covers
            ureg[i]      = dorow(qA[i], qB[i]);
            ureg[HR + i] = dorow(la, lb);
        }

        // ---- pairwise wave-combine tree (part4: 4 slots) ----
        if (wave >= 4) {
            float4* p4 = (float4*)part4[wave - 4];
            p4[lane] = ca0; p4[64+lane] = ca1; p4[128+lane] = cb0; p4[192+lane] = cb1;
        }
        __syncthreads();
        if (wave < 4) {
            const float4* p4 = (const float4*)part4[wave];
            float4 x0 = p4[lane], x1 = p4[64+lane], x2 = p4[128+lane], x3 = p4[192+lane];
            ADD4(ca0, x0); ADD4(ca1, x1); ADD4(cb0, x2); ADD4(cb1, x3);
        }
        if (wave == 2 || wave == 3) {     // rewrite own slot with combined val
            float4* p4 = (float4*)part4[wave];
            p4[lane] = ca0; p4[64+lane] = ca1; p4[128+lane] = cb0; p4[192+lane] = cb1;
        }
        __syncthreads();
        if (wave < 2) {
            const float4* p4 = (const float4*)part4[wave + 2];
            float4 x0 = p4[lane], x1 = p4[64+lane], x2 = p4[128+lane], x3 = p4[192+lane];
            ADD4(ca0, x0); ADD4(ca1, x1); ADD4(cb0, x2); ADD4(cb1, x3);
        }
        if (wave == 1) {
            float4* p4 = (float4*)part4[1];
            p4[lane] = ca0; p4[64+lane] = ca1; p4[128+lane] = cb0; p4[192+lane] = cb1;
        }
        if (tid == 0) sameflag = 1;
        __syncthreads();
        if (wave == 0) {
            const float4* p4 = (const float4*)part4[1];
            float4 x0 = p4[lane], x1 = p4[64+lane], x2 = p4[128+lane], x3 = p4[192+lane];
            ADD4(ca0, x0); ADD4(ca1, x1); ADD4(cb0, x2); ADD4(cb1, x3);
            float4* pg = (float4*)(partials + (((size_t)par * BS + b) * WPB + k) * M);
            pg[lane] = ca0; pg[64+lane] = ca1; pg[128+lane] = cb0; pg[192+lane] = cb1;
        }
        // ---- single 8-wide inter-WG barrier for this batch ----
        if (tid == 0) {
            __hip_atomic_fetch_add(mycnt, 1u, __ATOMIC_RELEASE,
                                   __HIP_MEMORY_SCOPE_AGENT);
            const unsigned tgt = (unsigned)WPB * (unsigned)(t + 1);
            while (__hip_atomic_load(mycnt, __ATOMIC_ACQUIRE,
                                     __HIP_MEMORY_SCOPE_AGENT) < tgt)
                __builtin_amdgcn_s_sleep(1);
        }
        __syncthreads();
        // ---- v = NU / sum_p partial[p] (fixed order; bitwise-identical in
        //      all 8 WGs -> uniform local early-exit decision) ----
        {
            const float2* pall = (const float2*)(partials +
                ((size_t)par * BS + b) * ((size_t)WPB * M));
            float2 s = pall[tid];
            #pragma unroll
            for (int p = 1; p < WPB; ++p) {
                float2 q = pall[(size_t)p * (M / 2) + tid];
                s.x += q.x; s.y += q.y;
            }
            float2 vnew = make_float2(NU / s.x, NU / s.y);
            if ((__float_as_uint(vnew.x) != __float_as_uint(vold.x)) ||
                (__float_as_uint(vnew.y) != __float_as_uint(vold.y)))
                sameflag = 0;
            vold = vnew;
            ((float2*)v_lds)[tid] = vnew;
        }
        __syncthreads();
        vra0 = v4[lane];       vra1 = v4[64 + lane];
        vrb0 = v4[128 + lane]; vrb1 = v4[192 + lane];
        converged = (sameflag != 0);   // bitwise fixed point: later iters identical
    }

    // ---- epilogue: Gamma*n = u' * Ghat * v * N (scales cancel) ----
    const float nN = (float)N;
    auto emit = [&](float* rowp, uint4 qa, uint4 qb, float un) {
        float2 g0 = upair(qa.x), g1 = upair(qa.y),
               g2 = upair(qa.z), g3 = upair(qa.w);
        float2 h0 = upair(qb.x), h1 = upair(qb.y),
               h2 = upair(qb.z), h3 = upair(qb.w);
        float4* o4 = (float4*)rowp;
        o4[lane]       = make_float4(un*g0.x*vra0.x, un*g0.y*vra0.y,
                                     un*g1.x*vra0.z, un*g1.y*vra0.w);
        o4[64 + lane]  = make_float4(un*g2.x*vra1.x, un*g2.y*vra1.y,
                                     un*g3.x*vra1.z, un*g3.y*vra1.w);
        o4[128 + lane] = make_float4(un*h0.x*vrb0.x, un*h0.y*vrb0.y,
                                     un*h1.x*vrb0.z, un*h1.y*vrb0.w);
        o4[192 + lane] = make_float4(un*h2.x*vrb1.x, un*h2.y*vrb1.y,
                                     un*h3.x*vrb1.z, un*h3.y*vrb1.w);
    };
    #pragma unroll
    for (int i = 0; i < HR; ++i) {
        const int row = wave * HR + i;
        emit(Gout + sl + (size_t)row * M, qA[i], qB[i], ureg[i] * nN);
    }
    #pragma unroll
    for (int i = 0; i < HL; ++i) {
        const int row = HROWS + wave * HL + i;
        uint4 la = Glds[wave * HL + i][lane];
        uint4 lb = Glds[wave * HL + i][64 + lane];
        emit(Gout + sl + (size_t)row * M, la, lb, ureg[HR + i] * nN);
    }
}

extern "C" void kernel_launch(void* const* d_in, const int* in_sizes, int n_in,
                              void* d_out, int out_size, void* d_ws, size_t ws_size,
                              hipStream_t stream) {
    (void)in_sizes; (void)n_in; (void)out_size;

    const float* C = (const float*)d_in[0];
    float* Gout = (float*)d_out;
    char* ws = (char*)d_ws;

    if (ws_size < WS_NEEDED) return;   // fail loudly (output stays poisoned)

    // Re-zero barrier counters every launch (graph-replay safe).
    hipMemsetAsync(d_ws, 0, CNT_BYTES, stream);

    unsigned* cnt   = (unsigned*)ws;
    float* partials = (float*)(ws + PART_OFF);
    sinkhorn_hybrid<<<dim3(BS * WPB), dim3(T), 0, stream>>>(
        C, Gout, cnt, partials);
}